// Round 5
// baseline (4475.898 us; speedup 1.0000x reference)
//
#include <hip/hip_runtime.h>
#include <stdint.h>
#include <stddef.h>

#define T_STEPS 128
#define F_IN 9
#define HID 128
#define OUT_N 12
#define XROW (T_STEPS * F_IN)  // 1152

typedef __attribute__((ext_vector_type(8))) short bf16x8;
typedef __attribute__((ext_vector_type(4))) float f32x4;

#define MFMA16(a, b, c) __builtin_amdgcn_mfma_f32_16x16x32_bf16((a), (b), (c), 0, 0, 0)

__device__ __forceinline__ short f2bf(float f) {
  union { float f; uint32_t u; } v; v.f = f;
  return (short)((v.u + 0x7fffu + ((v.u >> 16) & 1u)) >> 16);  // RNE
}
// Fast cell nonlinearities: raw v_exp_f32/v_rcp_f32 (quarter-rate, 1 op each).
// Round-4 used 1.0f/x which compiled to the 9-op precise-div sequence -> VALU-bound.
__device__ __forceinline__ float frcp(float x) { return __builtin_amdgcn_rcpf(x); }
__device__ __forceinline__ float sigm(float x) {
  return frcp(1.0f + __builtin_amdgcn_exp2f(-1.4426950408889634f * x));
}
__device__ __forceinline__ float tanh_f(float x) {
  return 1.0f - 2.0f * frcp(1.0f + __builtin_amdgcn_exp2f(2.8853900817779268f * x));
}

// ---------------- prep 1: W0x = Wih0 @ W_in  [512,9] -> B-frags; combined biases ----------------
// w0xf layout: [wcol][g][lane][8]  (per-column-slice 4 KB contiguous)
__global__ void prep_w0x(const float* __restrict__ W_in, const float* __restrict__ b_in,
                         const float* __restrict__ Wih0, const float* __restrict__ bih0,
                         const float* __restrict__ bhh0, const float* __restrict__ bih1,
                         const float* __restrict__ bhh1,
                         short* __restrict__ w0xf, float* __restrict__ b0x, float* __restrict__ b1) {
  int tid = threadIdx.x;             // 0..511
  int nt = tid >> 4, hl = tid & 15;  // global ntile, col-in-tile
  int w = nt >> 2, g = nt & 3;       // column-slice, gate
  int n = g * 128 + w * 16 + hl;     // original row of Wih0 (PyTorch i,f,g,o order)
  float wacc[F_IN];
#pragma unroll
  for (int f = 0; f < F_IN; ++f) wacc[f] = 0.f;
  float bacc = 0.f;
  for (int h = 0; h < HID; ++h) {
    float wv = Wih0[n * HID + h];
    bacc += wv * b_in[h];
#pragma unroll
    for (int f = 0; f < F_IN; ++f) wacc[f] += wv * W_in[h * F_IN + f];
  }
  b0x[n] = bacc + bih0[n] + bhh0[n];
  b1[n] = bih1[n] + bhh1[n];
#pragma unroll
  for (int k = 0; k < 32; ++k) {  // one K=32 tile, f<9 real, rest zero
    int quad = k >> 3, j = k & 7;
    w0xf[((w * 4 + g) * 64 + quad * 16 + hl) * 8 + j] = (k < F_IN) ? f2bf(wacc[k]) : (short)0;
  }
}

// ---------------- prep 2: per-column-slice frag layouts ----------------
// whh0f: [wcol][kt(4)][g(4)][lane][8]   (16 KB contiguous per slice)
// w1f:   [wcol][kt(8)][g(4)][lane][8]   (32 KB contiguous per slice; kt<4 = Wih1, kt>=4 = Whh1)
__global__ void prep_wrec(const float* __restrict__ Whh0, const float* __restrict__ Wih1,
                          const float* __restrict__ Whh1,
                          short* __restrict__ whh0f, short* __restrict__ w1f) {
  int gt = blockIdx.x * blockDim.x + threadIdx.x;  // 0..6143
  if (gt < 2048) {
    int kt = gt >> 9, rr = gt & 511;
    int nt = rr >> 4, hl = rr & 15;
    int w = nt >> 2, g = nt & 3;
    int n = g * 128 + w * 16 + hl;
#pragma unroll
    for (int k = 0; k < 32; ++k) {
      int quad = k >> 3, j = k & 7;
      whh0f[((w * 16 + kt * 4 + g) * 64 + quad * 16 + hl) * 8 + j] =
          f2bf(Whh0[n * HID + kt * 32 + k]);
    }
  } else {
    int g2 = gt - 2048;
    int kt = g2 >> 9, rr = g2 & 511;  // kt 0..7: k<128 -> Wih1, else Whh1
    int nt = rr >> 4, hl = rr & 15;
    int w = nt >> 2, g = nt & 3;
    int n = g * 128 + w * 16 + hl;
#pragma unroll
    for (int k = 0; k < 32; ++k) {
      int quad = k >> 3, j = k & 7;
      int kg = kt * 32 + k;
      float v = (kg < HID) ? Wih1[n * HID + kg] : Whh1[n * HID + kg - HID];
      w1f[((w * 32 + kt * 4 + g) * 64 + quad * 16 + hl) * 8 + j] = f2bf(v);
    }
  }
}

// ---------------- main: 256 blocks x 1024 thr (16 waves = 4/SIMD); block owns 64 batch rows ----
// Wave w: wcol = w&7 (16 h-cols x 4 gates), wmt = w>>3 (rows 32*wmt..32*wmt+31, 2 M-tiles).
// Weights streamed from L2 every step; 99 KB LDS forces 1 block/CU so 4 waves/SIMD = 128-reg
// budget, which the allocator targets anyway (rounds 1-4). Peak arch liveness ~85 + 32 acc.
__global__ void __launch_bounds__(1024) __attribute__((amdgpu_waves_per_eu(4, 4)))
lstm_main(const float* __restrict__ x, const short* __restrict__ w0xf,
          const short* __restrict__ whh0f, const short* __restrict__ w1f,
          const float* __restrict__ b0x, const float* __restrict__ b1,
          const float* __restrict__ Wout, const float* __restrict__ bout,
          float* __restrict__ out) {
  // h frags, A-operand-packed bf16, double buffered via pointer swap.
  // Each buffer: [4 mt][4 kt][64 lane][8] shorts = 8192 shorts (16 KB).
  __shared__ short sh[32768];        // 64 KB: h0A h0B h1A h1B
  __shared__ float h1fp[64 * HID];   // 32 KB, fp32 h1 at final step (pre-rounding)
  __shared__ float lg[64 * OUT_N];   // 3 KB logits

  const int tid = threadIdx.x;
  const int w = tid >> 6, lane = tid & 63;
  const int wcol = w & 7, wmt = w >> 3;
  const int quad = lane >> 4, c = lane & 15;
  const int rowbase = blockIdx.x * 64;

  {  // zero all h buffers (h_{-1} = 0)
    int* si = (int*)sh;
    for (int i = tid; i < 16384; i += 1024) si[i] = 0;
  }

  short* h0_cur = sh;            // written at t (phase 0)
  short* h0_prv = sh + 8192;     // read at t (phase 0)
  short* h1_cur = sh + 16384;    // written at t (phase 1)
  short* h1_prv = sh + 24576;    // read at t (phase 1)

  float bias0[4], bias1[4];
#pragma unroll
  for (int g = 0; g < 4; ++g) {
    int n = g * 128 + wcol * 16 + c;
    bias0[g] = b0x[n];
    bias1[g] = b1[n];
  }

  // per-slice weight stream bases (t-invariant, lane offset folded in)
  const short* wp0 = w0xf + (wcol * 4) * 512 + lane * 8;    // 4 frags, stride 512 shorts
  const short* wph = whh0f + (wcol * 16) * 512 + lane * 8;  // 16 frags
  const short* wp1 = w1f + (wcol * 32) * 512 + lane * 8;    // 32 frags

  // writer constants: this lane's h column is hcol = wcol*16 + c
  const int kt_w = wcol >> 1;
  const int klocal = ((wcol & 1) << 4) + c;
  const int quadA = klocal >> 3;
  const int jA = klocal & 7;
  const int wr_off = (kt_w * 64 + quadA * 16 + quad * 4) * 8 + jA;  // + mt*2048 + r*8

  float c0[8], c1[8];
#pragma unroll
  for (int i = 0; i < 8; ++i) { c0[i] = 0.f; c1[i] = 0.f; }

  __syncthreads();

#pragma clang loop unroll(disable)
  for (int t = 0; t < T_STEPS; ++t) {
    // ================= phase 0: g0 = b0x + x_t@W0x^T + h0_{t-1}@Whh0^T =================
    bf16x8 xf[2];
#pragma unroll
    for (int mtl = 0; mtl < 2; ++mtl) {
      const int mt = wmt * 2 + mtl;
      bf16x8 v;
#pragma unroll
      for (int j = 0; j < 8; ++j) v[j] = 0;
      if (quad == 0) {
        const float* xp = x + (size_t)(rowbase + mt * 16 + c) * XROW + t * F_IN;
#pragma unroll
        for (int j = 0; j < 8; ++j) v[j] = f2bf(xp[j]);
      } else if (quad == 1) {
        v[0] = f2bf(x[(size_t)(rowbase + mt * 16 + c) * XROW + t * F_IN + 8]);
      }
      xf[mtl] = v;
    }
    f32x4 acc[2][4];
#pragma unroll
    for (int mtl = 0; mtl < 2; ++mtl)
#pragma unroll
      for (int g = 0; g < 4; ++g) {
        f32x4 a; a[0] = bias0[g]; a[1] = bias0[g]; a[2] = bias0[g]; a[3] = bias0[g];
        acc[mtl][g] = a;
      }
    {  // x-projection: stream 4 gate frags
      bf16x8 b0_ = *(const bf16x8*)(wp0);
      bf16x8 b1_ = *(const bf16x8*)(wp0 + 512);
      bf16x8 b2_ = *(const bf16x8*)(wp0 + 1024);
      bf16x8 b3_ = *(const bf16x8*)(wp0 + 1536);
#pragma unroll
      for (int mtl = 0; mtl < 2; ++mtl) {
        acc[mtl][0] = MFMA16(xf[mtl], b0_, acc[mtl][0]);
        acc[mtl][1] = MFMA16(xf[mtl], b1_, acc[mtl][1]);
        acc[mtl][2] = MFMA16(xf[mtl], b2_, acc[mtl][2]);
        acc[mtl][3] = MFMA16(xf[mtl], b3_, acc[mtl][3]);
      }
    }
#pragma unroll
    for (int kt = 0; kt < 4; ++kt) {
      const short* wb = wph + kt * 2048;
      bf16x8 b0_ = *(const bf16x8*)(wb);
      bf16x8 b1_ = *(const bf16x8*)(wb + 512);
      bf16x8 b2_ = *(const bf16x8*)(wb + 1024);
      bf16x8 b3_ = *(const bf16x8*)(wb + 1536);
#pragma unroll
      for (int mtl = 0; mtl < 2; ++mtl) {
        bf16x8 af = *(const bf16x8*)(h0_prv + (((wmt * 2 + mtl) * 4 + kt) * 64 + lane) * 8);
        acc[mtl][0] = MFMA16(af, b0_, acc[mtl][0]);
        acc[mtl][1] = MFMA16(af, b1_, acc[mtl][1]);
        acc[mtl][2] = MFMA16(af, b2_, acc[mtl][2]);
        acc[mtl][3] = MFMA16(af, b3_, acc[mtl][3]);
      }
    }
    // cell 0 (fp32) + write h0_t frags
#pragma unroll
    for (int mtl = 0; mtl < 2; ++mtl)
#pragma unroll
      for (int r = 0; r < 4; ++r) {
        float gi = sigm(acc[mtl][0][r]);
        float gf = sigm(acc[mtl][1][r]);
        float gg = tanh_f(acc[mtl][2][r]);
        float go = sigm(acc[mtl][3][r]);
        float cn = gf * c0[mtl * 4 + r] + gi * gg;
        c0[mtl * 4 + r] = cn;
        float hn = go * tanh_f(cn);
        h0_cur[(wmt * 2 + mtl) * 2048 + r * 8 + wr_off] = f2bf(hn);
      }
    __syncthreads();
    // ================= phase 1: g1 = b1 + h0_t@Wih1^T + h1_{t-1}@Whh1^T =================
#pragma unroll
    for (int mtl = 0; mtl < 2; ++mtl)
#pragma unroll
      for (int g = 0; g < 4; ++g) {
        f32x4 a; a[0] = bias1[g]; a[1] = bias1[g]; a[2] = bias1[g]; a[3] = bias1[g];
        acc[mtl][g] = a;
      }
#pragma unroll
    for (int kt = 0; kt < 4; ++kt) {  // Wih1 part, A = h0_t
      const short* wb = wp1 + kt * 2048;
      bf16x8 b0_ = *(const bf16x8*)(wb);
      bf16x8 b1_ = *(const bf16x8*)(wb + 512);
      bf16x8 b2_ = *(const bf16x8*)(wb + 1024);
      bf16x8 b3_ = *(const bf16x8*)(wb + 1536);
#pragma unroll
      for (int mtl = 0; mtl < 2; ++mtl) {
        bf16x8 af = *(const bf16x8*)(h0_cur + (((wmt * 2 + mtl) * 4 + kt) * 64 + lane) * 8);
        acc[mtl][0] = MFMA16(af, b0_, acc[mtl][0]);
        acc[mtl][1] = MFMA16(af, b1_, acc[mtl][1]);
        acc[mtl][2] = MFMA16(af, b2_, acc[mtl][2]);
        acc[mtl][3] = MFMA16(af, b3_, acc[mtl][3]);
      }
    }
#pragma unroll
    for (int kt = 0; kt < 4; ++kt) {  // Whh1 part, A = h1_{t-1}
      const short* wb = wp1 + (kt + 4) * 2048;
      bf16x8 b0_ = *(const bf16x8*)(wb);
      bf16x8 b1_ = *(const bf16x8*)(wb + 512);
      bf16x8 b2_ = *(const bf16x8*)(wb + 1024);
      bf16x8 b3_ = *(const bf16x8*)(wb + 1536);
#pragma unroll
      for (int mtl = 0; mtl < 2; ++mtl) {
        bf16x8 af = *(const bf16x8*)(h1_prv + (((wmt * 2 + mtl) * 4 + kt) * 64 + lane) * 8);
        acc[mtl][0] = MFMA16(af, b0_, acc[mtl][0]);
        acc[mtl][1] = MFMA16(af, b1_, acc[mtl][1]);
        acc[mtl][2] = MFMA16(af, b2_, acc[mtl][2]);
        acc[mtl][3] = MFMA16(af, b3_, acc[mtl][3]);
      }
    }
    // cell 1 + write h1_t frags; fp32 h1 to LDS at final step only
#pragma unroll
    for (int mtl = 0; mtl < 2; ++mtl)
#pragma unroll
      for (int r = 0; r < 4; ++r) {
        float gi = sigm(acc[mtl][0][r]);
        float gf = sigm(acc[mtl][1][r]);
        float gg = tanh_f(acc[mtl][2][r]);
        float go = sigm(acc[mtl][3][r]);
        float cn = gf * c1[mtl * 4 + r] + gi * gg;
        c1[mtl * 4 + r] = cn;
        float hn = go * tanh_f(cn);
        if (t == T_STEPS - 1)
          h1fp[((wmt * 2 + mtl) * 16 + quad * 4 + r) * HID + wcol * 16 + c] = hn;
        h1_cur[(wmt * 2 + mtl) * 2048 + r * 8 + wr_off] = f2bf(hn);
      }
    __syncthreads();
    // swap double buffers
    short* tp = h0_cur; h0_cur = h0_prv; h0_prv = tp;
    tp = h1_cur; h1_cur = h1_prv; h1_prv = tp;
  }

  // ================= epilogue: logits = h1 @ Wout^T + bout, softmax over 12 =================
  {
    int row = tid >> 4, og = tid & 15;
    if (og < OUT_N) {
      float s = bout[og];
      const float* wo = Wout + og * HID;
      const float* hr = h1fp + row * HID;
#pragma unroll 8
      for (int k = 0; k < HID; ++k) s += hr[k] * wo[k];
      lg[row * OUT_N + og] = s;
    }
  }
  __syncthreads();
  if (tid < 64) {
    int row = tid;
    float m = lg[row * OUT_N];
#pragma unroll
    for (int oc = 1; oc < OUT_N; ++oc) m = fmaxf(m, lg[row * OUT_N + oc]);
    float e[OUT_N];
    float s = 0.f;
#pragma unroll
    for (int oc = 0; oc < OUT_N; ++oc) {
      e[oc] = __expf(lg[row * OUT_N + oc] - m);
      s += e[oc];
    }
    float inv = 1.0f / s;
    float* orow = out + (size_t)(rowbase + row) * OUT_N;
#pragma unroll
    for (int oc = 0; oc < OUT_N; ++oc) orow[oc] = e[oc] * inv;
  }
}

extern "C" void kernel_launch(void* const* d_in, const int* in_sizes, int n_in,
                              void* d_out, int out_size, void* d_ws, size_t ws_size,
                              hipStream_t stream) {
  const float* x    = (const float*)d_in[0];
  const float* W_in = (const float*)d_in[1];
  const float* b_in = (const float*)d_in[2];
  const float* Wih0 = (const float*)d_in[3];
  const float* Whh0 = (const float*)d_in[4];
  const float* bih0 = (const float*)d_in[5];
  const float* bhh0 = (const float*)d_in[6];
  const float* Wih1 = (const float*)d_in[7];
  const float* Whh1 = (const float*)d_in[8];
  const float* bih1 = (const float*)d_in[9];
  const float* bhh1 = (const float*)d_in[10];
  const float* Wout = (const float*)d_in[11];
  const float* bout = (const float*)d_in[12];
  float* out = (float*)d_out;

  // workspace layout (~420 KB): frag-packed bf16 weights + combined biases
  short* w0xf  = (short*)d_ws;            // 16384 shorts (32 KB)
  short* whh0f = w0xf + 16384;            // 65536 shorts (128 KB)
  short* w1f   = whh0f + 65536;           // 131072 shorts (256 KB)
  float* b0x   = (float*)(w1f + 131072);  // 512 f32
  float* b1    = b0x + 512;               // 512 f32

  prep_w0x<<<1, 512, 0, stream>>>(W_in, b_in, Wih0, bih0, bhh0, bih1, bhh1, w0xf, b0x, b1);
  prep_wrec<<<12, 512, 0, stream>>>(Whh0, Wih1, Whh1, whh0f, w1f);
  lstm_main<<<256, 1024, 0, stream>>>(x, w0xf, whh0f, w1f, b0x, b1, Wout, bout, out);
}

// Round 6
// 1396.920 us; speedup vs baseline: 3.2041x; 3.2041x over previous
//
#include <hip/hip_runtime.h>
#include <stdint.h>
#include <stddef.h>

#define T_STEPS 128
#define F_IN 9
#define HID 128
#define OUT_N 12
#define XROW (T_STEPS * F_IN)  // 1152

typedef __attribute__((ext_vector_type(8))) short bf16x8;
typedef __attribute__((ext_vector_type(4))) float f32x4;

#define MFMA16(a, b, c) __builtin_amdgcn_mfma_f32_16x16x32_bf16((a), (b), (c), 0, 0, 0)

__device__ __forceinline__ short f2bf(float f) {
  union { float f; uint32_t u; } v; v.f = f;
  return (short)((v.u + 0x7fffu + ((v.u >> 16) & 1u)) >> 16);  // RNE
}
// Fast cell nonlinearities: raw v_exp_f32 / v_rcp_f32 (single quarter-rate ops).
// Round 4 used 1.0f/x -> 9-op precise-div sequence -> VALU-bound (69% busy).
__device__ __forceinline__ float frcp(float x) { return __builtin_amdgcn_rcpf(x); }
__device__ __forceinline__ float sigm(float x) {
  return frcp(1.0f + __builtin_amdgcn_exp2f(-1.4426950408889634f * x));
}
__device__ __forceinline__ float tanh_f(float x) {
  return 1.0f - 2.0f * frcp(1.0f + __builtin_amdgcn_exp2f(2.8853900817779268f * x));
}

// ---------------- prep 1: W0x = Wih0 @ W_in  [512,9] -> B-frags; combined biases ----------------
// w0xf layout: [w][g][lane][8]  (per-wave 4 KB contiguous)
__global__ void prep_w0x(const float* __restrict__ W_in, const float* __restrict__ b_in,
                         const float* __restrict__ Wih0, const float* __restrict__ bih0,
                         const float* __restrict__ bhh0, const float* __restrict__ bih1,
                         const float* __restrict__ bhh1,
                         short* __restrict__ w0xf, float* __restrict__ b0x, float* __restrict__ b1) {
  int tid = threadIdx.x;             // 0..511
  int nt = tid >> 4, hl = tid & 15;  // global ntile, col-in-tile
  int w = nt >> 2, g = nt & 3;       // wave slice, gate
  int n = g * 128 + w * 16 + hl;     // original row of Wih0 (PyTorch i,f,g,o order)
  float wacc[F_IN];
#pragma unroll
  for (int f = 0; f < F_IN; ++f) wacc[f] = 0.f;
  float bacc = 0.f;
  for (int h = 0; h < HID; ++h) {
    float wv = Wih0[n * HID + h];
    bacc += wv * b_in[h];
#pragma unroll
    for (int f = 0; f < F_IN; ++f) wacc[f] += wv * W_in[h * F_IN + f];
  }
  b0x[n] = bacc + bih0[n] + bhh0[n];
  b1[n] = bih1[n] + bhh1[n];
#pragma unroll
  for (int k = 0; k < 32; ++k) {  // one K=32 tile, f<9 real, rest zero
    int quad = k >> 3, j = k & 7;
    w0xf[((w * 4 + g) * 64 + quad * 16 + hl) * 8 + j] = (k < F_IN) ? f2bf(wacc[k]) : (short)0;
  }
}

// ---------------- prep 2: per-wave-contiguous frag layouts ----------------
// whh0f: [w][kt(4)][g(4)][lane][8]   (per-wave 16 KB contiguous)
// w1f:   [w][kt(8)][g(4)][lane][8]   (per-wave 32 KB contiguous; kt<4 = Wih1, kt>=4 = Whh1)
__global__ void prep_wrec(const float* __restrict__ Whh0, const float* __restrict__ Wih1,
                          const float* __restrict__ Whh1,
                          short* __restrict__ whh0f, short* __restrict__ w1f) {
  int gt = blockIdx.x * blockDim.x + threadIdx.x;  // 0..6143
  if (gt < 2048) {
    int kt = gt >> 9, rr = gt & 511;
    int nt = rr >> 4, hl = rr & 15;
    int w = nt >> 2, g = nt & 3;
    int n = g * 128 + w * 16 + hl;
#pragma unroll
    for (int k = 0; k < 32; ++k) {
      int quad = k >> 3, j = k & 7;
      whh0f[((w * 16 + kt * 4 + g) * 64 + quad * 16 + hl) * 8 + j] =
          f2bf(Whh0[n * HID + kt * 32 + k]);
    }
  } else {
    int g2 = gt - 2048;
    int kt = g2 >> 9, rr = g2 & 511;  // kt 0..7: k<128 -> Wih1, else Whh1
    int nt = rr >> 4, hl = rr & 15;
    int w = nt >> 2, g = nt & 3;
    int n = g * 128 + w * 16 + hl;
#pragma unroll
    for (int k = 0; k < 32; ++k) {
      int quad = k >> 3, j = k & 7;
      int kg = kt * 32 + k;
      float v = (kg < HID) ? Wih1[n * HID + kg] : Whh1[n * HID + kg - HID];
      w1f[((w * 32 + kt * 4 + g) * 64 + quad * 16 + hl) * 8 + j] = f2bf(v);
    }
  }
}

// ---------------- main: 256 blocks x 512 thr (8 waves = 2/SIMD); block owns 64 batch rows ----
// This is round-4's proven spill-free configuration (108 arch + 64 acc VGPRs, FETCH 39 MB).
// Round 5 proved 1024-thr blocks force a 128-reg budget -> catastrophic spills. Do not raise
// occupancy; cut VALU work instead (fast transcendentals above).
__global__ void __launch_bounds__(512) __attribute__((amdgpu_waves_per_eu(2)))
lstm_main(const float* __restrict__ x, const short* __restrict__ w0xf,
          const short* __restrict__ whh0f, const short* __restrict__ w1f,
          const float* __restrict__ b0x, const float* __restrict__ b1,
          const float* __restrict__ Wout, const float* __restrict__ bout,
          float* __restrict__ out) {
  // h frags, A-operand-packed bf16, double buffered via pointer swap.
  // Each buffer: [4 mt][4 kt][64 lane][8] shorts = 8192 shorts (16 KB).
  __shared__ short sh[32768];        // 64 KB: h0A h0B h1A h1B
  __shared__ float h1fp[64 * HID];   // 32 KB, fp32 h1 at final step (pre-rounding)
  __shared__ float lg[64 * OUT_N];   // 3 KB logits

  const int tid = threadIdx.x;
  const int w = tid >> 6, lane = tid & 63;
  const int quad = lane >> 4, c = lane & 15;
  const int rowbase = blockIdx.x * 64;

  {  // zero all h buffers (h_{-1} = 0)
    int* si = (int*)sh;
    for (int i = tid; i < 16384; i += 512) si[i] = 0;
  }

  short* h0_cur = sh;            // written at t (phase 0)
  short* h0_prv = sh + 8192;     // read at t (phase 0)
  short* h1_cur = sh + 16384;    // written at t (phase 1)
  short* h1_prv = sh + 24576;    // read at t (phase 1)

  float bias0[4], bias1[4];
#pragma unroll
  for (int g = 0; g < 4; ++g) {
    int n = g * 128 + w * 16 + c;
    bias0[g] = b0x[n];
    bias1[g] = b1[n];
  }

  // per-wave weight stream bases (t-invariant, lane offset folded in)
  const short* wp0 = w0xf + (w * 4) * 512 + lane * 8;    // 4 frags, stride 512 shorts
  const short* wph = whh0f + (w * 16) * 512 + lane * 8;  // 16 frags
  const short* wp1 = w1f + (w * 32) * 512 + lane * 8;    // 32 frags

  // writer constants: this lane's h column is hcol = w*16 + c
  const int kt_w = w >> 1;
  const int klocal = ((w & 1) << 4) + c;
  const int quadA = klocal >> 3;
  const int jA = klocal & 7;
  const int wr_off = (kt_w * 64 + quadA * 16 + quad * 4) * 8 + jA;  // + mt*2048 + r*8

  float c0[16], c1[16];
#pragma unroll
  for (int i = 0; i < 16; ++i) { c0[i] = 0.f; c1[i] = 0.f; }

  __syncthreads();

#pragma clang loop unroll(disable)
  for (int t = 0; t < T_STEPS; ++t) {
    // ================= phase 0: g0 = b0x + x_t@W0x^T + h0_{t-1}@Whh0^T =================
    bf16x8 xf[4];
#pragma unroll
    for (int mt = 0; mt < 4; ++mt) {
      bf16x8 v;
#pragma unroll
      for (int j = 0; j < 8; ++j) v[j] = 0;
      if (quad == 0) {
        const float* xp = x + (size_t)(rowbase + mt * 16 + c) * XROW + t * F_IN;
#pragma unroll
        for (int j = 0; j < 8; ++j) v[j] = f2bf(xp[j]);
      } else if (quad == 1) {
        v[0] = f2bf(x[(size_t)(rowbase + mt * 16 + c) * XROW + t * F_IN + 8]);
      }
      xf[mt] = v;
    }
    f32x4 acc[4][4];
#pragma unroll
    for (int mt = 0; mt < 4; ++mt)
#pragma unroll
      for (int g = 0; g < 4; ++g) {
        f32x4 a; a[0] = bias0[g]; a[1] = bias0[g]; a[2] = bias0[g]; a[3] = bias0[g];
        acc[mt][g] = a;
      }
    {  // x-projection: stream 4 gate frags
      bf16x8 b0_ = *(const bf16x8*)(wp0);
      bf16x8 b1_ = *(const bf16x8*)(wp0 + 512);
      bf16x8 b2_ = *(const bf16x8*)(wp0 + 1024);
      bf16x8 b3_ = *(const bf16x8*)(wp0 + 1536);
#pragma unroll
      for (int mt = 0; mt < 4; ++mt) {
        acc[mt][0] = MFMA16(xf[mt], b0_, acc[mt][0]);
        acc[mt][1] = MFMA16(xf[mt], b1_, acc[mt][1]);
        acc[mt][2] = MFMA16(xf[mt], b2_, acc[mt][2]);
        acc[mt][3] = MFMA16(xf[mt], b3_, acc[mt][3]);
      }
    }
#pragma clang loop unroll_count(2)
    for (int kt = 0; kt < 4; ++kt) {
      const short* wb = wph + kt * 2048;
      bf16x8 b0_ = *(const bf16x8*)(wb);
      bf16x8 b1_ = *(const bf16x8*)(wb + 512);
      bf16x8 b2_ = *(const bf16x8*)(wb + 1024);
      bf16x8 b3_ = *(const bf16x8*)(wb + 1536);
#pragma unroll
      for (int mt = 0; mt < 4; ++mt) {
        bf16x8 af = *(const bf16x8*)(h0_prv + ((mt * 4 + kt) * 64 + lane) * 8);
        acc[mt][0] = MFMA16(af, b0_, acc[mt][0]);
        acc[mt][1] = MFMA16(af, b1_, acc[mt][1]);
        acc[mt][2] = MFMA16(af, b2_, acc[mt][2]);
        acc[mt][3] = MFMA16(af, b3_, acc[mt][3]);
      }
    }
    // cell 0 (fp32) + write h0_t frags
#pragma unroll
    for (int mt = 0; mt < 4; ++mt)
#pragma unroll
      for (int r = 0; r < 4; ++r) {
        float gi = sigm(acc[mt][0][r]);
        float gf = sigm(acc[mt][1][r]);
        float gg = tanh_f(acc[mt][2][r]);
        float go = sigm(acc[mt][3][r]);
        float cn = gf * c0[mt * 4 + r] + gi * gg;
        c0[mt * 4 + r] = cn;
        float hn = go * tanh_f(cn);
        h0_cur[mt * 2048 + r * 8 + wr_off] = f2bf(hn);
      }
    __syncthreads();
    // ================= phase 1: g1 = b1 + h0_t@Wih1^T + h1_{t-1}@Whh1^T =================
#pragma unroll
    for (int mt = 0; mt < 4; ++mt)
#pragma unroll
      for (int g = 0; g < 4; ++g) {
        f32x4 a; a[0] = bias1[g]; a[1] = bias1[g]; a[2] = bias1[g]; a[3] = bias1[g];
        acc[mt][g] = a;
      }
#pragma clang loop unroll_count(2)
    for (int kt = 0; kt < 4; ++kt) {  // Wih1 part, A = h0_t
      const short* wb = wp1 + kt * 2048;
      bf16x8 b0_ = *(const bf16x8*)(wb);
      bf16x8 b1_ = *(const bf16x8*)(wb + 512);
      bf16x8 b2_ = *(const bf16x8*)(wb + 1024);
      bf16x8 b3_ = *(const bf16x8*)(wb + 1536);
#pragma unroll
      for (int mt = 0; mt < 4; ++mt) {
        bf16x8 af = *(const bf16x8*)(h0_cur + ((mt * 4 + kt) * 64 + lane) * 8);
        acc[mt][0] = MFMA16(af, b0_, acc[mt][0]);
        acc[mt][1] = MFMA16(af, b1_, acc[mt][1]);
        acc[mt][2] = MFMA16(af, b2_, acc[mt][2]);
        acc[mt][3] = MFMA16(af, b3_, acc[mt][3]);
      }
    }
#pragma clang loop unroll_count(2)
    for (int kt = 0; kt < 4; ++kt) {  // Whh1 part, A = h1_{t-1}
      const short* wb = wp1 + (kt + 4) * 2048;
      bf16x8 b0_ = *(const bf16x8*)(wb);
      bf16x8 b1_ = *(const bf16x8*)(wb + 512);
      bf16x8 b2_ = *(const bf16x8*)(wb + 1024);
      bf16x8 b3_ = *(const bf16x8*)(wb + 1536);
#pragma unroll
      for (int mt = 0; mt < 4; ++mt) {
        bf16x8 af = *(const bf16x8*)(h1_prv + ((mt * 4 + kt) * 64 + lane) * 8);
        acc[mt][0] = MFMA16(af, b0_, acc[mt][0]);
        acc[mt][1] = MFMA16(af, b1_, acc[mt][1]);
        acc[mt][2] = MFMA16(af, b2_, acc[mt][2]);
        acc[mt][3] = MFMA16(af, b3_, acc[mt][3]);
      }
    }
    // cell 1 + write h1_t frags; fp32 h1 to LDS at final step only
#pragma unroll
    for (int mt = 0; mt < 4; ++mt)
#pragma unroll
      for (int r = 0; r < 4; ++r) {
        float gi = sigm(acc[mt][0][r]);
        float gf = sigm(acc[mt][1][r]);
        float gg = tanh_f(acc[mt][2][r]);
        float go = sigm(acc[mt][3][r]);
        float cn = gf * c1[mt * 4 + r] + gi * gg;
        c1[mt * 4 + r] = cn;
        float hn = go * tanh_f(cn);
        if (t == T_STEPS - 1) h1fp[(mt * 16 + quad * 4 + r) * HID + w * 16 + c] = hn;
        h1_cur[mt * 2048 + r * 8 + wr_off] = f2bf(hn);
      }
    __syncthreads();
    // swap double buffers
    short* tp = h0_cur; h0_cur = h0_prv; h0_prv = tp;
    tp = h1_cur; h1_cur = h1_prv; h1_prv = tp;
  }

  // ================= epilogue: logits = h1 @ Wout^T + bout, softmax over 12 =================
  {
    int row = tid >> 3, og = tid & 7;
    for (int oc = og; oc < OUT_N; oc += 8) {
      float s = bout[oc];
      const float* wo = Wout + oc * HID;
      const float* hr = h1fp + row * HID;
#pragma unroll 8
      for (int k = 0; k < HID; ++k) s += hr[k] * wo[k];
      lg[row * OUT_N + oc] = s;
    }
  }
  __syncthreads();
  if (tid < 64) {
    int row = tid;
    float m = lg[row * OUT_N];
#pragma unroll
    for (int oc = 1; oc < OUT_N; ++oc) m = fmaxf(m, lg[row * OUT_N + oc]);
    float e[OUT_N];
    float s = 0.f;
#pragma unroll
    for (int oc = 0; oc < OUT_N; ++oc) {
      e[oc] = __expf(lg[row * OUT_N + oc] - m);
      s += e[oc];
    }
    float inv = 1.0f / s;
    float* orow = out + (size_t)(rowbase + row) * OUT_N;
#pragma unroll
    for (int oc = 0; oc < OUT_N; ++oc) orow[oc] = e[oc] * inv;
  }
}

extern "C" void kernel_launch(void* const* d_in, const int* in_sizes, int n_in,
                              void* d_out, int out_size, void* d_ws, size_t ws_size,
                              hipStream_t stream) {
  const float* x    = (const float*)d_in[0];
  const float* W_in = (const float*)d_in[1];
  const float* b_in = (const float*)d_in[2];
  const float* Wih0 = (const float*)d_in[3];
  const float* Whh0 = (const float*)d_in[4];
  const float* bih0 = (const float*)d_in[5];
  const float* bhh0 = (const float*)d_in[6];
  const float* Wih1 = (const float*)d_in[7];
  const float* Whh1 = (const float*)d_in[8];
  const float* bih1 = (const float*)d_in[9];
  const float* bhh1 = (const float*)d_in[10];
  const float* Wout = (const float*)d_in[11];
  const float* bout = (const float*)d_in[12];
  float* out = (float*)d_out;

  // workspace layout (~420 KB): frag-packed bf16 weights + combined biases
  short* w0xf  = (short*)d_ws;            // 16384 shorts (32 KB)
  short* whh0f = w0xf + 16384;            // 65536 shorts (128 KB)
  short* w1f   = whh0f + 65536;           // 131072 shorts (256 KB)
  float* b0x   = (float*)(w1f + 131072);  // 512 f32
  float* b1    = b0x + 512;               // 512 f32

  prep_w0x<<<1, 512, 0, stream>>>(W_in, b_in, Wih0, bih0, bhh0, bih1, bhh1, w0xf, b0x, b1);
  prep_wrec<<<12, 512, 0, stream>>>(Whh0, Wih1, Whh1, whh0f, w1f);
  lstm_main<<<256, 512, 0, stream>>>(x, w0xf, whh0f, w1f, b0x, b1, Wout, bout, out);
}